// Round 20
// baseline (623.522 us; speedup 1.0000x reference)
//
#include <hip/hip_runtime.h>
#include <math.h>

#define T_TOK 32768
#define DM 512
#define DFF 2048
#define NE 8
#define MAXT 264   // sum ceil(ce/256) <= 65536/256 + 8

typedef __attribute__((ext_vector_type(8))) short short8;
typedef __attribute__((ext_vector_type(4))) float f32x4;

__device__ __forceinline__ unsigned int f2bf1(float f) {
  union { float f; unsigned int u; } x; x.f = f;
  return (x.u + 0x7fffu + ((x.u >> 16) & 1u)) >> 16;  // RNE
}

#define GLOAD(src, dst) \
  __builtin_amdgcn_global_load_lds((const __attribute__((address_space(1))) unsigned int*)(src), \
                                   (__attribute__((address_space(3))) unsigned int*)(dst), 16, 0, 0)
#define WAITVM(N) asm volatile("s_waitcnt vmcnt(" #N ")" ::: "memory")
#define BARRIER() asm volatile("s_barrier" ::: "memory")

// transpose + convert: src [E][R][C] f32 -> dst [E][C][R] bf16
// PERM=1: apply within-32 k-permutation pi(c5)=((c5&15)<<1)|(c5>>4) to dst last-dim
template <int PERM>
__global__ void tcvt_kernel(const float* __restrict__ src, unsigned short* __restrict__ dst,
                            int R, int C) {
  __shared__ float tile[32][33];
  int e = blockIdx.z;
  const float* s = src + (size_t)e * R * C;
  unsigned short* d = dst + (size_t)e * R * C;
  int c0 = blockIdx.x * 32, r0 = blockIdx.y * 32;
  int tx = threadIdx.x, ty = threadIdx.y;
#pragma unroll
  for (int i = 0; i < 4; ++i)
    tile[ty + i * 8][tx] = s[(size_t)(r0 + ty + i * 8) * C + c0 + tx];
  __syncthreads();
#pragma unroll
  for (int i = 0; i < 4; ++i) {
    int rr = r0 + tx;
    if (PERM) rr = (rr & ~31) | ((rr & 15) << 1) | ((rr >> 4) & 1);
    d[(size_t)(c0 + ty + i * 8) * R + rr] = (unsigned short)f2bf1(tile[tx][ty + i * 8]);
  }
}

// gating: 16 tokens per block (wave/token); emits x as bf16 + expert buckets
__global__ __launch_bounds__(1024) void gate_kernel(
    const float* __restrict__ x, const float* __restrict__ gw,
    int* __restrict__ cnt, int* __restrict__ tok, float* __restrict__ wgt,
    unsigned int* __restrict__ xb) {
  __shared__ int lcnt[NE];
  __shared__ int lbase[NE];
  __shared__ int wslot[16][2];
  __shared__ int winfo[16][2];
  __shared__ float wval[16][2];
  int tid = threadIdx.x;
  int wid = tid >> 6, lane = tid & 63;
  int t = blockIdx.x * 16 + wid;
  if (tid < NE) lcnt[tid] = 0;
  __syncthreads();

  float acc[NE];
#pragma unroll
  for (int e = 0; e < NE; ++e) acc[e] = 0.f;
  const float* xr = x + (size_t)t * DM;
  unsigned int* xbr = xb + (size_t)t * (DM / 2);
#pragma unroll
  for (int j = 0; j < 4; ++j) {
    int d0 = j * 128 + lane * 2;
    float2 xv = *(const float2*)(xr + d0);
    const float* g0 = gw + d0 * NE;
#pragma unroll
    for (int e = 0; e < NE; ++e) acc[e] += xv.x * g0[e] + xv.y * g0[NE + e];
    xbr[j * 64 + lane] = f2bf1(xv.x) | (f2bf1(xv.y) << 16);
  }
#pragma unroll
  for (int off = 32; off >= 1; off >>= 1) {
#pragma unroll
    for (int e = 0; e < NE; ++e) acc[e] += __shfl_xor(acc[e], off);
  }
  if (lane == 0) {
    int e0 = 0; float l0 = acc[0];
#pragma unroll
    for (int e = 1; e < NE; ++e) if (acc[e] > l0) { l0 = acc[e]; e0 = e; }
    int e1 = (e0 == 0) ? 1 : 0; float l1 = acc[e1];
#pragma unroll
    for (int e = 0; e < NE; ++e) if (e != e0 && acc[e] > l1) { l1 = acc[e]; e1 = e; }
    float w0 = 1.f / (1.f + expf(l1 - l0));   // renormalized top-2, exact
    winfo[wid][0] = e0; winfo[wid][1] = e1;
    wval[wid][0] = w0;  wval[wid][1] = 1.f - w0;
    wslot[wid][0] = atomicAdd(&lcnt[e0], 1);
    wslot[wid][1] = atomicAdd(&lcnt[e1], 1);
  }
  __syncthreads();
  if (tid < NE) lbase[tid] = atomicAdd(&cnt[tid * 64], lcnt[tid]);
  __syncthreads();
  if (lane == 0) {
    int e0 = winfo[wid][0], e1 = winfo[wid][1];
    int p0 = lbase[e0] + wslot[wid][0];
    int p1 = lbase[e1] + wslot[wid][1];
    tok[e0 * T_TOK + p0] = t; wgt[e0 * T_TOK + p0] = wval[wid][0];
    tok[e1 * T_TOK + p1] = t; wgt[e1 * T_TOK + p1] = wval[wid][1];
  }
}

// prefix over 256-row tiles: tile_base[e] = sum_{k<e} ceil(cnt[k]/256)
__global__ void plan_kernel(const int* __restrict__ cnt, int* __restrict__ tile_base) {
  if (threadIdx.x == 0 && blockIdx.x == 0) {
    int tb = 0;
    for (int e = 0; e < NE; ++e) { tile_base[e] = tb; tb += (cnt[e * 64] + 255) >> 8; }
    tile_base[NE] = tb;
  }
}

// GEMM1: H[slot][pi(f)] = gelu(gather(xb) @ w1t^T + b1)
// 256x256 tile, 512 thr / 8 waves (2Mx4N, wave tile 128x64), K=512 (16 steps of 32);
// 4-buffer (32KB each) depth-3 ring, counted vmcnt(8). 32 MFMA/wave/barrier.
__global__ __launch_bounds__(512, 2) void gemm1_kernel(
    const unsigned int* __restrict__ xb, const unsigned short* __restrict__ w1t,
    const float* __restrict__ b1, const int* __restrict__ cnt,
    const int* __restrict__ tok, const int* __restrict__ tile_base,
    unsigned short* __restrict__ H, int tile_lo) {
  int nwg = (int)gridDim.x;
  int bid0 = (int)blockIdx.x;
  int bid = (bid0 & 7) * (nwg >> 3) + (bid0 >> 3);   // XCD-contiguous (nwg%8==0)
  int nt = bid & 7;
  int gt = tile_lo + (bid >> 3);
  if (gt >= tile_base[NE]) return;
  int e = 0;
#pragma unroll
  for (int k = 0; k < NE - 1; ++k) e += (gt >= tile_base[k + 1]) ? 1 : 0;
  int tloc = gt - tile_base[e];
  int ce = cnt[e * 64];
  int m0 = tloc * 256;
  int n0 = nt * 256;

  __shared__ char Lds[4 * 32768];   // 4 buffers: A 16KB + B 16KB each

  int tid = (int)threadIdx.x;
  int lane = tid & 63;
  int wid = tid >> 6;               // 0..7
  int wm = wid & 1, wn = wid >> 1;  // 2M x 4N, wave tile 128x64
  int fl = lane & 15, q = lane >> 4;
  int sxy = ((q ^ ((fl >> 1) & 3)) << 4);

  // staging: row r = tid>>2 (0..127) + second load at row+128; slot sl = tid&3,
  // global source slot XOR-swizzled by (r>>1)&3 (invariant under +128).
  const int* tokg = tok + e * T_TOK;
  int r = tid >> 2, sl = tid & 3;
  int ss = sl ^ ((r >> 1) & 3);
  int t0 = tokg[min(m0 + r, ce - 1)];
  int t1 = tokg[min(m0 + 128 + r, ce - 1)];
  const char* asrc0 = (const char*)xb + (size_t)t0 * 1024 + ss * 16;
  const char* asrc1 = (const char*)xb + (size_t)t1 * 1024 + ss * 16;
  const char* bsrc0 = (const char*)w1t + ((size_t)e * DFF + n0 + r) * 1024 + ss * 16;
  const char* bsrc1 = (const char*)w1t + ((size_t)e * DFF + n0 + 128 + r) * 1024 + ss * 16;

  int aoff[8], boff[4];
#pragma unroll
  for (int i = 0; i < 8; ++i) aoff[i] = (wm * 128 + i * 16 + fl) * 64 + sxy;
#pragma unroll
  for (int j = 0; j < 4; ++j) boff[j] = 16384 + (wn * 64 + j * 16 + fl) * 64 + sxy;

  f32x4 acc[8][4];
#pragma unroll
  for (int a = 0; a < 8; ++a)
#pragma unroll
    for (int b = 0; b < 4; ++b) acc[a][b] = (f32x4){0.f, 0.f, 0.f, 0.f};

#define STAGE1(bi, ti) do { \
    char* base_ = Lds + (bi) * 32768; size_t ko_ = (size_t)(ti) * 64; \
    GLOAD(asrc0 + ko_, base_ + tid * 16);         \
    GLOAD(asrc1 + ko_, base_ + 8192 + tid * 16);  \
    GLOAD(bsrc0 + ko_, base_ + 16384 + tid * 16); \
    GLOAD(bsrc1 + ko_, base_ + 24576 + tid * 16); } while (0)

#define COMP1(bi) do { \
    const char* base_ = Lds + (bi) * 32768; \
    short8 a[8], b[4]; \
    _Pragma("unroll") for (int i = 0; i < 8; ++i) a[i] = *(const short8*)(base_ + aoff[i]); \
    _Pragma("unroll") for (int j = 0; j < 4; ++j) b[j] = *(const short8*)(base_ + boff[j]); \
    _Pragma("unroll") for (int mf = 0; mf < 8; ++mf) \
    _Pragma("unroll") for (int nf = 0; nf < 4; ++nf) \
      acc[mf][nf] = __builtin_amdgcn_mfma_f32_16x16x32_bf16(a[mf], b[nf], acc[mf][nf], 0, 0, 0); \
  } while (0)

#define STEP1(t, sb, cb) do { \
    WAITVM(8); BARRIER(); STAGE1(sb, (t) + 3); COMP1(cb); } while (0)

  STAGE1(0, 0); STAGE1(1, 1); STAGE1(2, 2);   // 12 loads in flight (depth-3)
  for (int tt = 0; tt < 12; tt += 4) {        // t = 0..11, stages tiles 3..14
    STEP1(tt + 0, 3, 0);
    STEP1(tt + 1, 0, 1);
    STEP1(tt + 2, 1, 2);
    STEP1(tt + 3, 2, 3);
  }
  WAITVM(8); BARRIER(); STAGE1(3, 15); COMP1(0);   // t=12
  WAITVM(8); BARRIER(); COMP1(1);                  // t=13
  WAITVM(4); BARRIER(); COMP1(2);                  // t=14
  WAITVM(0); BARRIER(); COMP1(3);                  // t=15
#undef STEP1
#undef STAGE1
#undef COMP1

  // epilogue: bias + tanh-gelu; paired u32 stores at pi-permuted k positions
  size_t hrow0 = (size_t)(gt - tile_lo) * 256;
  float bv[4];
#pragma unroll
  for (int nf = 0; nf < 4; ++nf) bv[nf] = b1[e * DFF + n0 + wn * 64 + nf * 16 + fl];
#pragma unroll
  for (int mf = 0; mf < 8; ++mf)
#pragma unroll
    for (int j = 0; j < 4; ++j) {
      int row = wm * 128 + mf * 16 + q * 4 + j;
      float g[4];
#pragma unroll
      for (int nf = 0; nf < 4; ++nf) {
        float v = acc[mf][nf][j] + bv[nf];
        float u2 = v * (1.5957691216f + 0.0713548162f * v * v);
        g[nf] = v / (1.f + __expf(-u2));
      }
      unsigned int* Hp = (unsigned int*)(H + (hrow0 + row) * DFF + n0 + wn * 64);
      Hp[fl]      = f2bf1(g[0]) | (f2bf1(g[1]) << 16);
      Hp[16 + fl] = f2bf1(g[2]) | (f2bf1(g[3]) << 16);
    }
}

// GEMM2: out[tok[slot]] += wgt[slot]*(H @ w2t^T + b2)
// 256x256 tile, 512 thr / 8 waves, K=2048 (64 steps); same 4-buffer depth-3 ring.
__global__ __launch_bounds__(512, 2) void gemm2_kernel(
    const unsigned short* __restrict__ H, const unsigned short* __restrict__ w2t,
    const float* __restrict__ b2, const int* __restrict__ cnt,
    const int* __restrict__ tok, const float* __restrict__ wgt,
    const int* __restrict__ tile_base, float* __restrict__ out, int tile_lo) {
  int nwg = (int)gridDim.x;
  int bid0 = (int)blockIdx.x;
  int bid = (bid0 & 7) * (nwg >> 3) + (bid0 >> 3);   // XCD-contiguous (nwg%8==0)
  int nt = bid & 1;
  int gt = tile_lo + (bid >> 1);
  if (gt >= tile_base[NE]) return;
  int e = 0;
#pragma unroll
  for (int k = 0; k < NE - 1; ++k) e += (gt >= tile_base[k + 1]) ? 1 : 0;
  int tloc = gt - tile_base[e];
  int ce = cnt[e * 64];
  int m0 = tloc * 256;
  int n0 = nt * 256;

  __shared__ char Lds[4 * 32768];

  int tid = (int)threadIdx.x;
  int lane = tid & 63;
  int wid = tid >> 6;
  int wm = wid & 1, wn = wid >> 1;
  int fl = lane & 15, q = lane >> 4;
  int sxy = ((q ^ ((fl >> 1) & 3)) << 4);

  size_t hrow0 = (size_t)(gt - tile_lo) * 256;
  int r = tid >> 2, sl = tid & 3;
  int ss = sl ^ ((r >> 1) & 3);
  const char* asrc0 = (const char*)H + (hrow0 + r) * 4096 + ss * 16;
  const char* asrc1 = (const char*)H + (hrow0 + 128 + r) * 4096 + ss * 16;
  const char* bsrc0 = (const char*)w2t + ((size_t)e * DM + n0 + r) * 4096 + ss * 16;
  const char* bsrc1 = (const char*)w2t + ((size_t)e * DM + n0 + 128 + r) * 4096 + ss * 16;

  int aoff[8], boff[4];
#pragma unroll
  for (int i = 0; i < 8; ++i) aoff[i] = (wm * 128 + i * 16 + fl) * 64 + sxy;
#pragma unroll
  for (int j = 0; j < 4; ++j) boff[j] = 16384 + (wn * 64 + j * 16 + fl) * 64 + sxy;

  f32x4 acc[8][4];
#pragma unroll
  for (int a = 0; a < 8; ++a)
#pragma unroll
    for (int b = 0; b < 4; ++b) acc[a][b] = (f32x4){0.f, 0.f, 0.f, 0.f};

#define STAGE2(bi, ti) do { \
    char* base_ = Lds + (bi) * 32768; size_t ko_ = (size_t)(ti) * 64; \
    GLOAD(asrc0 + ko_, base_ + tid * 16);         \
    GLOAD(asrc1 + ko_, base_ + 8192 + tid * 16);  \
    GLOAD(bsrc0 + ko_, base_ + 16384 + tid * 16); \
    GLOAD(bsrc1 + ko_, base_ + 24576 + tid * 16); } while (0)

#define COMP2(bi) do { \
    const char* base_ = Lds + (bi) * 32768; \
    short8 a[8], b[4]; \
    _Pragma("unroll") for (int i = 0; i < 8; ++i) a[i] = *(const short8*)(base_ + aoff[i]); \
    _Pragma("unroll") for (int j = 0; j < 4; ++j) b[j] = *(const short8*)(base_ + boff[j]); \
    _Pragma("unroll") for (int mf = 0; mf < 8; ++mf) \
    _Pragma("unroll") for (int nf = 0; nf < 4; ++nf) \
      acc[mf][nf] = __builtin_amdgcn_mfma_f32_16x16x32_bf16(a[mf], b[nf], acc[mf][nf], 0, 0, 0); \
  } while (0)

#define STEP2(t, sb, cb) do { \
    WAITVM(8); BARRIER(); STAGE2(sb, (t) + 3); COMP2(cb); } while (0)

  STAGE2(0, 0); STAGE2(1, 1); STAGE2(2, 2);   // 12 loads in flight (depth-3)
  for (int tt = 0; tt < 60; tt += 4) {        // t = 0..59, stages tiles 3..62
    STEP2(tt + 0, 3, 0);
    STEP2(tt + 1, 0, 1);
    STEP2(tt + 2, 1, 2);
    STEP2(tt + 3, 2, 3);
  }
  WAITVM(8); BARRIER(); STAGE2(3, 63); COMP2(0);   // t=60
  WAITVM(8); BARRIER(); COMP2(1);                  // t=61
  WAITVM(4); BARRIER(); COMP2(2);                  // t=62
  WAITVM(0); BARRIER(); COMP2(3);                  // t=63
#undef STEP2
#undef STAGE2
#undef COMP2

  const int* tokg = tok + e * T_TOK;
  const float* wgtg = wgt + e * T_TOK;
  float bias2[4];
#pragma unroll
  for (int nf = 0; nf < 4; ++nf) bias2[nf] = b2[e * DM + n0 + wn * 64 + nf * 16 + fl];
#pragma unroll
  for (int mf = 0; mf < 8; ++mf)
#pragma unroll
    for (int j = 0; j < 4; ++j) {
      int row = wm * 128 + mf * 16 + q * 4 + j;
      int slot = m0 + row;
      if (slot < ce) {
        int tk = tokg[slot];
        float w = wgtg[slot];
        float* orow = out + (size_t)tk * DM + n0 + wn * 64;
#pragma unroll
        for (int nf = 0; nf < 4; ++nf)
          atomicAdd(orow + nf * 16 + fl, w * (acc[mf][nf][j] + bias2[nf]));
      }
    }
}

extern "C" void kernel_launch(void* const* d_in, const int* in_sizes, int n_in,
                              void* d_out, int out_size, void* d_ws, size_t ws_size,
                              hipStream_t stream) {
  (void)in_sizes; (void)n_in; (void)out_size;
  const float* x  = (const float*)d_in[0];
  const float* gw = (const float*)d_in[1];
  const float* w1 = (const float*)d_in[2];
  const float* b1 = (const float*)d_in[3];
  const float* w2 = (const float*)d_in[4];
  const float* b2 = (const float*)d_in[5];
  float* out = (float*)d_out;

  char* ws = (char*)d_ws;
  size_t off = 0;
  auto alloc = [&](size_t sz) { char* p = ws + off; off += (sz + 255) & ~(size_t)255; return p; };
  int*   cnt = (int*)alloc(NE * 64 * 4);
  int*   tok = (int*)alloc((size_t)NE * T_TOK * 4);
  float* wgt = (float*)alloc((size_t)NE * T_TOK * 4);
  int*   tile_base = (int*)alloc((NE + 1) * 4);
  unsigned int* xb = (unsigned int*)alloc((size_t)T_TOK * (DM / 2) * 4);
  unsigned short* w1t = (unsigned short*)alloc((size_t)NE * DFF * DM * 2);
  unsigned short* w2t = (unsigned short*)alloc((size_t)NE * DM * DFF * 2);

  // Chunking: TPC=128 (256-row tiles) -> gemm1 grid 1024 = 4.0 rounds at 1 blk/CU,
  // gemm2 grid 256 = 1.0 round. Chunks: 128/128/8. Halve TPC if ws too small.
  size_t avail = (ws_size > off) ? (ws_size - off) : 0;
  int TPC = 128;
  while (TPC > 4 && (size_t)TPC * 256 * DFF * 2 > avail) TPC >>= 1;
  unsigned short* H = (unsigned short*)alloc((size_t)TPC * 256 * DFF * 2);

  hipMemsetAsync(cnt, 0, NE * 64 * 4, stream);
  hipMemsetAsync(out, 0, (size_t)T_TOK * DM * 4, stream);

  tcvt_kernel<0><<<dim3(DFF / 32, DM / 32, NE), dim3(32, 8), 0, stream>>>(w1, w1t, DM, DFF);
  tcvt_kernel<1><<<dim3(DM / 32, DFF / 32, NE), dim3(32, 8), 0, stream>>>(w2, w2t, DFF, DM);
  gate_kernel<<<T_TOK / 16, 1024, 0, stream>>>(x, gw, cnt, tok, wgt, xb);
  plan_kernel<<<1, 64, 0, stream>>>(cnt, tile_base);

  for (int lo = 0; lo < MAXT; lo += TPC) {
    gemm1_kernel<<<TPC * 8, 512, 0, stream>>>(xb, w1t, b1, cnt, tok, tile_base, H, lo);
    gemm2_kernel<<<TPC * 2, 512, 0, stream>>>(H, w2t, b2, cnt, tok, wgt, tile_base, out, lo);
  }
}

// Round 21
// 564.780 us; speedup vs baseline: 1.1040x; 1.1040x over previous
//
#include <hip/hip_runtime.h>
#include <math.h>

#define T_TOK 32768
#define DM 512
#define DFF 2048
#define NE 8
#define MAXTILES 528   // >= sum ceil(ce/128) worst case (65536/128 + 8)

typedef __attribute__((ext_vector_type(8))) short short8;
typedef __attribute__((ext_vector_type(4))) float f32x4;

__device__ __forceinline__ unsigned int f2bf1(float f) {
  union { float f; unsigned int u; } x; x.f = f;
  return (x.u + 0x7fffu + ((x.u >> 16) & 1u)) >> 16;  // RNE
}

#define GLOAD(src, dst) \
  __builtin_amdgcn_global_load_lds((const __attribute__((address_space(1))) unsigned int*)(src), \
                                   (__attribute__((address_space(3))) unsigned int*)(dst), 16, 0, 0)
#define WAITVM(N) asm volatile("s_waitcnt vmcnt(" #N ")" ::: "memory")
#define BARRIER() asm volatile("s_barrier" ::: "memory")

// transpose + convert: src [E][R][C] f32 -> dst [E][C][R] bf16
// PERM=1: apply within-32 k-permutation pi(c5)=((c5&15)<<1)|(c5>>4) to dst last-dim
template <int PERM>
__global__ void tcvt_kernel(const float* __restrict__ src, unsigned short* __restrict__ dst,
                            int R, int C) {
  __shared__ float tile[32][33];
  int e = blockIdx.z;
  const float* s = src + (size_t)e * R * C;
  unsigned short* d = dst + (size_t)e * R * C;
  int c0 = blockIdx.x * 32, r0 = blockIdx.y * 32;
  int tx = threadIdx.x, ty = threadIdx.y;
#pragma unroll
  for (int i = 0; i < 4; ++i)
    tile[ty + i * 8][tx] = s[(size_t)(r0 + ty + i * 8) * C + c0 + tx];
  __syncthreads();
#pragma unroll
  for (int i = 0; i < 4; ++i) {
    int rr = r0 + tx;
    if (PERM) rr = (rr & ~31) | ((rr & 15) << 1) | ((rr >> 4) & 1);
    d[(size_t)(c0 + ty + i * 8) * R + rr] = (unsigned short)f2bf1(tile[tx][ty + i * 8]);
  }
}

// gating: 16 tokens per block (wave/token); emits x as bf16 + expert buckets
__global__ __launch_bounds__(1024) void gate_kernel(
    const float* __restrict__ x, const float* __restrict__ gw,
    int* __restrict__ cnt, int* __restrict__ tok, float* __restrict__ wgt,
    unsigned int* __restrict__ xb) {
  __shared__ int lcnt[NE];
  __shared__ int lbase[NE];
  __shared__ int wslot[16][2];
  __shared__ int winfo[16][2];
  __shared__ float wval[16][2];
  int tid = threadIdx.x;
  int wid = tid >> 6, lane = tid & 63;
  int t = blockIdx.x * 16 + wid;
  if (tid < NE) lcnt[tid] = 0;
  __syncthreads();

  float acc[NE];
#pragma unroll
  for (int e = 0; e < NE; ++e) acc[e] = 0.f;
  const float* xr = x + (size_t)t * DM;
  unsigned int* xbr = xb + (size_t)t * (DM / 2);
#pragma unroll
  for (int j = 0; j < 4; ++j) {
    int d0 = j * 128 + lane * 2;
    float2 xv = *(const float2*)(xr + d0);
    const float* g0 = gw + d0 * NE;
#pragma unroll
    for (int e = 0; e < NE; ++e) acc[e] += xv.x * g0[e] + xv.y * g0[NE + e];
    xbr[j * 64 + lane] = f2bf1(xv.x) | (f2bf1(xv.y) << 16);
  }
#pragma unroll
  for (int off = 32; off >= 1; off >>= 1) {
#pragma unroll
    for (int e = 0; e < NE; ++e) acc[e] += __shfl_xor(acc[e], off);
  }
  if (lane == 0) {
    int e0 = 0; float l0 = acc[0];
#pragma unroll
    for (int e = 1; e < NE; ++e) if (acc[e] > l0) { l0 = acc[e]; e0 = e; }
    int e1 = (e0 == 0) ? 1 : 0; float l1 = acc[e1];
#pragma unroll
    for (int e = 0; e < NE; ++e) if (e != e0 && acc[e] > l1) { l1 = acc[e]; e1 = e; }
    float w0 = 1.f / (1.f + expf(l1 - l0));   // renormalized top-2, exact
    winfo[wid][0] = e0; winfo[wid][1] = e1;
    wval[wid][0] = w0;  wval[wid][1] = 1.f - w0;
    wslot[wid][0] = atomicAdd(&lcnt[e0], 1);
    wslot[wid][1] = atomicAdd(&lcnt[e1], 1);
  }
  __syncthreads();
  if (tid < NE) lbase[tid] = atomicAdd(&cnt[tid * 64], lcnt[tid]);
  __syncthreads();
  if (lane == 0) {
    int e0 = winfo[wid][0], e1 = winfo[wid][1];
    int p0 = lbase[e0] + wslot[wid][0];
    int p1 = lbase[e1] + wslot[wid][1];
    tok[e0 * T_TOK + p0] = t; wgt[e0 * T_TOK + p0] = wval[wid][0];
    tok[e1 * T_TOK + p1] = t; wgt[e1 * T_TOK + p1] = wval[wid][1];
  }
}

// prefix over tiles: tile_base[e] = sum_{k<e} ceil(cnt[k]/128)
__global__ void plan_kernel(const int* __restrict__ cnt, int* __restrict__ tile_base) {
  if (threadIdx.x == 0 && blockIdx.x == 0) {
    int tb = 0;
    for (int e = 0; e < NE; ++e) { tile_base[e] = tb; tb += (cnt[e * 64] + 127) >> 7; }
    tile_base[NE] = tb;
  }
}

// ---- GEMM1 body: H[slot][pi(f)] = gelu(gather(xb) @ w1t^T + b1)
// 128x128, K=512 (16 steps); 5-buffer depth-4 ring, counted vmcnt(12). (R17 body.)
__device__ __forceinline__ void gemm1_body(
    char* Lds, int bid0, int nwg,
    const unsigned int* __restrict__ xb, const unsigned short* __restrict__ w1t,
    const float* __restrict__ b1, const int* __restrict__ cnt,
    const int* __restrict__ tok, const int* __restrict__ tile_base,
    unsigned short* __restrict__ H, int tile_lo) {
  int bid = (bid0 & 7) * (nwg >> 3) + (bid0 >> 3);   // XCD-contiguous (nwg%8==0)
  int nt = bid & 15;
  int gt = tile_lo + (bid >> 4);
  if (gt >= tile_base[NE]) return;
  int e = 0;
#pragma unroll
  for (int k = 0; k < NE - 1; ++k) e += (gt >= tile_base[k + 1]) ? 1 : 0;
  int tloc = gt - tile_base[e];
  int ce = cnt[e * 64];
  int m0 = tloc * 128;
  int n0 = nt * 128;

  int tid = (int)threadIdx.x;
  int lane = tid & 63;
  int wid = tid >> 6;
  int wm = wid & 1, wn = wid >> 1;
  int fl = lane & 15, q = lane >> 4;
  int sxy = ((q ^ ((fl >> 1) & 3)) << 4);

  const int* tokg = tok + e * T_TOK;
  int r0 = tid >> 2, r1 = 64 + (tid >> 2);
  int sl = tid & 3;
  int ss0 = sl ^ ((r0 >> 1) & 3);
  int ss1 = sl ^ ((r1 >> 1) & 3);
  int t0 = tokg[min(m0 + r0, ce - 1)];
  int t1 = tokg[min(m0 + r1, ce - 1)];
  const char* asrc0 = (const char*)xb + (size_t)t0 * 1024 + ss0 * 16;
  const char* asrc1 = (const char*)xb + (size_t)t1 * 1024 + ss1 * 16;
  const char* bsrc0 = (const char*)w1t + ((size_t)e * DFF + n0 + r0) * 1024 + ss0 * 16;
  const char* bsrc1 = (const char*)w1t + ((size_t)e * DFF + n0 + r1) * 1024 + ss1 * 16;

  int aoff[4], boff[4];
#pragma unroll
  for (int i = 0; i < 4; ++i) {
    aoff[i] = (wm * 64 + i * 16 + fl) * 64 + sxy;
    boff[i] = 8192 + (wn * 64 + i * 16 + fl) * 64 + sxy;
  }

  f32x4 acc[4][4];
#pragma unroll
  for (int a = 0; a < 4; ++a)
#pragma unroll
    for (int b = 0; b < 4; ++b) acc[a][b] = (f32x4){0.f, 0.f, 0.f, 0.f};

#define STAGE1(bi, ti) do { \
    char* base_ = Lds + (bi) * 16384; size_t ko_ = (size_t)(ti) * 64; \
    GLOAD(asrc0 + ko_, base_ + tid * 16);        \
    GLOAD(asrc1 + ko_, base_ + 4096 + tid * 16); \
    GLOAD(bsrc0 + ko_, base_ + 8192 + tid * 16); \
    GLOAD(bsrc1 + ko_, base_ + 12288 + tid * 16); } while (0)

#define COMP1(bi) do { \
    const char* base_ = Lds + (bi) * 16384; \
    short8 a[4], b[4]; \
    _Pragma("unroll") for (int i = 0; i < 4; ++i) { \
      a[i] = *(const short8*)(base_ + aoff[i]); \
      b[i] = *(const short8*)(base_ + boff[i]); } \
    _Pragma("unroll") for (int mf = 0; mf < 4; ++mf) \
    _Pragma("unroll") for (int nf = 0; nf < 4; ++nf) \
      acc[mf][nf] = __builtin_amdgcn_mfma_f32_16x16x32_bf16(a[mf], b[nf], acc[mf][nf], 0, 0, 0); \
  } while (0)

#define STEP1(t, sb, cb) do { \
    WAITVM(12); BARRIER(); STAGE1(sb, (t) + 4); COMP1(cb); } while (0)

  STAGE1(0, 0); STAGE1(1, 1); STAGE1(2, 2); STAGE1(3, 3);
  for (int tt = 0; tt < 10; tt += 5) {        // t = 0..9, stages tiles 4..13
    STEP1(tt + 0, 4, 0);
    STEP1(tt + 1, 0, 1);
    STEP1(tt + 2, 1, 2);
    STEP1(tt + 3, 2, 3);
    STEP1(tt + 4, 3, 4);
  }
  STEP1(10, 4, 0);                                 // stages tile 14
  STEP1(11, 0, 1);                                 // stages tile 15
  WAITVM(12); BARRIER(); COMP1(2);                 // t=12
  WAITVM(8);  BARRIER(); COMP1(3);                 // t=13
  WAITVM(4);  BARRIER(); COMP1(4);                 // t=14
  WAITVM(0);  BARRIER(); COMP1(0);                 // t=15
#undef STEP1
#undef STAGE1
#undef COMP1

  size_t hrow0 = (size_t)(gt - tile_lo) * 128;
  float bv[4];
#pragma unroll
  for (int nf = 0; nf < 4; ++nf) bv[nf] = b1[e * DFF + n0 + wn * 64 + nf * 16 + fl];
#pragma unroll
  for (int mf = 0; mf < 4; ++mf)
#pragma unroll
    for (int j = 0; j < 4; ++j) {
      int row = wm * 64 + mf * 16 + q * 4 + j;
      float g[4];
#pragma unroll
      for (int nf = 0; nf < 4; ++nf) {
        float v = acc[mf][nf][j] + bv[nf];
        float u2 = v * (1.5957691216f + 0.0713548162f * v * v);
        g[nf] = v / (1.f + __expf(-u2));
      }
      unsigned int* Hp = (unsigned int*)(H + (hrow0 + row) * DFF + n0 + wn * 64);
      Hp[fl]      = f2bf1(g[0]) | (f2bf1(g[1]) << 16);
      Hp[16 + fl] = f2bf1(g[2]) | (f2bf1(g[3]) << 16);
    }
}

// ---- GEMM2 body: out[tok[slot]] += wgt[slot]*(H @ w2t^T + b2)
// K=2048 (64 steps); 5-buffer depth-4 ring, counted vmcnt(12). (R17 body.)
__device__ __forceinline__ void gemm2_body(
    char* Lds, int bid0, int nwg,
    const unsigned short* __restrict__ H, const unsigned short* __restrict__ w2t,
    const float* __restrict__ b2, const int* __restrict__ cnt,
    const int* __restrict__ tok, const float* __restrict__ wgt,
    const int* __restrict__ tile_base, float* __restrict__ out, int tile_lo) {
  int bid = (bid0 & 7) * (nwg >> 3) + (bid0 >> 3);   // XCD-contiguous (nwg%8==0)
  int nt = bid & 3;
  int gt = tile_lo + (bid >> 2);
  if (gt >= tile_base[NE]) return;
  int e = 0;
#pragma unroll
  for (int k = 0; k < NE - 1; ++k) e += (gt >= tile_base[k + 1]) ? 1 : 0;
  int tloc = gt - tile_base[e];
  int ce = cnt[e * 64];
  int m0 = tloc * 128;
  int n0 = nt * 128;

  int tid = (int)threadIdx.x;
  int lane = tid & 63;
  int wid = tid >> 6;
  int wm = wid & 1, wn = wid >> 1;
  int fl = lane & 15, q = lane >> 4;
  int sxy = ((q ^ ((fl >> 1) & 3)) << 4);

  int r0 = tid >> 2, r1 = 64 + (tid >> 2);
  int sl = tid & 3;
  int ss0 = sl ^ ((r0 >> 1) & 3);
  int ss1 = sl ^ ((r1 >> 1) & 3);
  size_t hrow0 = (size_t)(gt - tile_lo) * 128;
  const char* asrc0 = (const char*)H + (hrow0 + r0) * 4096 + ss0 * 16;
  const char* asrc1 = (const char*)H + (hrow0 + r1) * 4096 + ss1 * 16;
  const char* bsrc0 = (const char*)w2t + ((size_t)e * DM + n0 + r0) * 4096 + ss0 * 16;
  const char* bsrc1 = (const char*)w2t + ((size_t)e * DM + n0 + r1) * 4096 + ss1 * 16;

  int aoff[4], boff[4];
#pragma unroll
  for (int i = 0; i < 4; ++i) {
    aoff[i] = (wm * 64 + i * 16 + fl) * 64 + sxy;
    boff[i] = 8192 + (wn * 64 + i * 16 + fl) * 64 + sxy;
  }

  f32x4 acc[4][4];
#pragma unroll
  for (int a = 0; a < 4; ++a)
#pragma unroll
    for (int b = 0; b < 4; ++b) acc[a][b] = (f32x4){0.f, 0.f, 0.f, 0.f};

#define STAGE2(bi, ti) do { \
    char* base_ = Lds + (bi) * 16384; size_t ko_ = (size_t)(ti) * 64; \
    GLOAD(asrc0 + ko_, base_ + tid * 16);        \
    GLOAD(asrc1 + ko_, base_ + 4096 + tid * 16); \
    GLOAD(bsrc0 + ko_, base_ + 8192 + tid * 16); \
    GLOAD(bsrc1 + ko_, base_ + 12288 + tid * 16); } while (0)

#define COMP2(bi) do { \
    const char* base_ = Lds + (bi) * 16384; \
    short8 a[4], b[4]; \
    _Pragma("unroll") for (int i = 0; i < 4; ++i) { \
      a[i] = *(const short8*)(base_ + aoff[i]); \
      b[i] = *(const short8*)(base_ + boff[i]); } \
    _Pragma("unroll") for (int mf = 0; mf < 4; ++mf) \
    _Pragma("unroll") for (int nf = 0; nf < 4; ++nf) \
      acc[mf][nf] = __builtin_amdgcn_mfma_f32_16x16x32_bf16(a[mf], b[nf], acc[mf][nf], 0, 0, 0); \
  } while (0)

#define STEP2(t, sb, cb) do { \
    WAITVM(12); BARRIER(); STAGE2(sb, (t) + 4); COMP2(cb); } while (0)

  STAGE2(0, 0); STAGE2(1, 1); STAGE2(2, 2); STAGE2(3, 3);
  for (int tt = 0; tt < 60; tt += 5) {        // t = 0..59, stages tiles 4..63
    STEP2(tt + 0, 4, 0);
    STEP2(tt + 1, 0, 1);
    STEP2(tt + 2, 1, 2);
    STEP2(tt + 3, 2, 3);
    STEP2(tt + 4, 3, 4);
  }
  WAITVM(12); BARRIER(); COMP2(0);                 // t=60
  WAITVM(8);  BARRIER(); COMP2(1);                 // t=61
  WAITVM(4);  BARRIER(); COMP2(2);                 // t=62
  WAITVM(0);  BARRIER(); COMP2(3);                 // t=63
#undef STEP2
#undef STAGE2
#undef COMP2

  const int* tokg = tok + e * T_TOK;
  const float* wgtg = wgt + e * T_TOK;
  float bias2[4];
#pragma unroll
  for (int nf = 0; nf < 4; ++nf) bias2[nf] = b2[e * DM + n0 + wn * 64 + nf * 16 + fl];
#pragma unroll
  for (int mf = 0; mf < 4; ++mf)
#pragma unroll
    for (int j = 0; j < 4; ++j) {
      int row = wm * 64 + mf * 16 + q * 4 + j;
      int slot = m0 + row;
      if (slot < ce) {
        int tk = tokg[slot];
        float w = wgtg[slot];
        float* orow = out + (size_t)tk * DM + n0 + wn * 64;
#pragma unroll
        for (int nf = 0; nf < 4; ++nf)
          atomicAdd(orow + nf * 16 + fl, w * (acc[mf][nf][j] + bias2[nf]));
      }
    }
}

// merged launch: first g1 blocks run gemm1(chunk c), rest run gemm2(chunk c-1).
// Fills each other's ramp/drain rounds; same-stream ordering guarantees H(c-1) ready.
__global__ __launch_bounds__(256) void moe_kernel(
    const unsigned int* __restrict__ xb,
    const unsigned short* __restrict__ w1t, const float* __restrict__ b1,
    const unsigned short* __restrict__ w2t, const float* __restrict__ b2,
    const int* __restrict__ cnt, const int* __restrict__ tok,
    const float* __restrict__ wgt, const int* __restrict__ tile_base,
    unsigned short* __restrict__ H1, int tile_lo1, int g1,
    const unsigned short* __restrict__ H2, int tile_lo2,
    float* __restrict__ out) {
  __shared__ char Lds[5 * 16384];
  int b = (int)blockIdx.x;
  if (b < g1) {
    gemm1_body(Lds, b, g1, xb, w1t, b1, cnt, tok, tile_base, H1, tile_lo1);
  } else {
    gemm2_body(Lds, b - g1, (int)gridDim.x - g1, H2, w2t, b2, cnt, tok, wgt,
               tile_base, out, tile_lo2);
  }
}

extern "C" void kernel_launch(void* const* d_in, const int* in_sizes, int n_in,
                              void* d_out, int out_size, void* d_ws, size_t ws_size,
                              hipStream_t stream) {
  (void)in_sizes; (void)n_in; (void)out_size;
  const float* x  = (const float*)d_in[0];
  const float* gw = (const float*)d_in[1];
  const float* w1 = (const float*)d_in[2];
  const float* b1 = (const float*)d_in[3];
  const float* w2 = (const float*)d_in[4];
  const float* b2 = (const float*)d_in[5];
  float* out = (float*)d_out;

  char* ws = (char*)d_ws;
  size_t off = 0;
  auto alloc = [&](size_t sz) { char* p = ws + off; off += (sz + 255) & ~(size_t)255; return p; };
  int*   cnt = (int*)alloc(NE * 64 * 4);
  int*   tok = (int*)alloc((size_t)NE * T_TOK * 4);
  float* wgt = (float*)alloc((size_t)NE * T_TOK * 4);
  int*   tile_base = (int*)alloc((NE + 1) * 4);
  unsigned int* xb = (unsigned int*)alloc((size_t)T_TOK * (DM / 2) * 4);
  unsigned short* w1t = (unsigned short*)alloc((size_t)NE * DFF * DM * 2);
  unsigned short* w2t = (unsigned short*)alloc((size_t)NE * DM * DFF * 2);

  // TPC=128, two H slots (ping-pong). Merged grid per launch = TPC*16 + TPC*4
  // = 2560 = exactly 5.0 rounds at 2 blk/CU; gemm2 of chunk c-1 fills gemm1(c)'s
  // ramp/drain. Halve TPC if ws too small for 2 slots.
  size_t avail = (ws_size > off) ? (ws_size - off) : 0;
  int TPC = 128;
  while (TPC > 4 && 2 * (size_t)TPC * 128 * DFF * 2 > avail) TPC >>= 1;
  size_t slotE = (size_t)TPC * 128 * DFF;
  unsigned short* Hb = (unsigned short*)alloc(2 * slotE * 2);
  int NC = (MAXTILES + TPC - 1) / TPC;

  hipMemsetAsync(cnt, 0, NE * 64 * 4, stream);
  hipMemsetAsync(out, 0, (size_t)T_TOK * DM * 4, stream);

  tcvt_kernel<0><<<dim3(DFF / 32, DM / 32, NE), dim3(32, 8), 0, stream>>>(w1, w1t, DM, DFF);
  tcvt_kernel<1><<<dim3(DM / 32, DFF / 32, NE), dim3(32, 8), 0, stream>>>(w2, w2t, DFF, DM);
  gate_kernel<<<T_TOK / 16, 1024, 0, stream>>>(x, gw, cnt, tok, wgt, xb);
  plan_kernel<<<1, 64, 0, stream>>>(cnt, tile_base);

  for (int c = 0; c <= NC; ++c) {
    int g1 = (c < NC) ? TPC * 16 : 0;
    int g2 = (c > 0) ? TPC * 4 : 0;
    unsigned short* H1 = Hb + (size_t)(c & 1) * slotE;
    const unsigned short* H2 = Hb + (size_t)((c + 1) & 1) * slotE;
    moe_kernel<<<g1 + g2, 256, 0, stream>>>(xb, w1t, b1, w2t, b2, cnt, tok, wgt,
                                            tile_base, H1, c * TPC, g1,
                                            H2, (c - 1) * TPC, out);
  }
}

// Round 22
// 550.723 us; speedup vs baseline: 1.1322x; 1.0255x over previous
//
#include <hip/hip_runtime.h>
#include <math.h>

#define T_TOK 32768
#define DM 512
#define DFF 2048
#define NE 8
#define MAXTILES 528   // >= sum ceil(ce/128) worst case (65536/128 + 8)

typedef __attribute__((ext_vector_type(8))) short short8;
typedef __attribute__((ext_vector_type(4))) float f32x4;

__device__ __forceinline__ unsigned int f2bf1(float f) {
  union { float f; unsigned int u; } x; x.f = f;
  return (x.u + 0x7fffu + ((x.u >> 16) & 1u)) >> 16;  // RNE
}

#define GLOAD(src, dst) \
  __builtin_amdgcn_global_load_lds((const __attribute__((address_space(1))) unsigned int*)(src), \
                                   (__attribute__((address_space(3))) unsigned int*)(dst), 16, 0, 0)
#define WAITVM(N) asm volatile("s_waitcnt vmcnt(" #N ")" ::: "memory")
#define BARRIER() asm volatile("s_barrier" ::: "memory")

// merged transpose+convert for BOTH weight tensors (one launch):
// id>>13==0: w1 [E][DM][DFF] -> w1t [E][DFF][DM]  (no perm)
// id>>13==1: w2 [E][DFF][DM] -> w2t [E][DM][DFF]  (pi perm on dst last-dim:
//            pi(c5)=((c5&15)<<1)|(c5>>4), matching gemm1's paired H store)
__global__ void tcvt_all_kernel(const float* __restrict__ w1, const float* __restrict__ w2,
                                unsigned short* __restrict__ w1t,
                                unsigned short* __restrict__ w2t) {
  __shared__ float tile[32][33];
  int id = (int)blockIdx.x;
  int which = id >> 13;
  int rem = id & 8191;
  int e = rem >> 10;
  int t = rem & 1023;
  const float* src; unsigned short* dst; int R, C, c0, r0;
  if (which == 0) { src = w1; dst = w1t; R = DM;  C = DFF; c0 = (t & 63) * 32; r0 = (t >> 6) * 32; }
  else            { src = w2; dst = w2t; R = DFF; C = DM;  c0 = (t & 15) * 32; r0 = (t >> 4) * 32; }
  const float* s = src + (size_t)e * R * C;
  unsigned short* d = dst + (size_t)e * R * C;
  int tx = threadIdx.x, ty = threadIdx.y;
#pragma unroll
  for (int i = 0; i < 4; ++i)
    tile[ty + i * 8][tx] = s[(size_t)(r0 + ty + i * 8) * C + c0 + tx];
  __syncthreads();
#pragma unroll
  for (int i = 0; i < 4; ++i) {
    int rr = r0 + tx;
    if (which == 1) rr = (rr & ~31) | ((rr & 15) << 1) | ((rr >> 4) & 1);
    d[(size_t)(c0 + ty + i * 8) * R + rr] = (unsigned short)f2bf1(tile[tx][ty + i * 8]);
  }
}

// gating: 16 tokens per block (wave/token); emits x as bf16 + expert buckets
__global__ __launch_bounds__(1024) void gate_kernel(
    const float* __restrict__ x, const float* __restrict__ gw,
    int* __restrict__ cnt, int* __restrict__ tok, float* __restrict__ wgt,
    unsigned int* __restrict__ xb) {
  __shared__ int lcnt[NE];
  __shared__ int lbase[NE];
  __shared__ int wslot[16][2];
  __shared__ int winfo[16][2];
  __shared__ float wval[16][2];
  int tid = threadIdx.x;
  int wid = tid >> 6, lane = tid & 63;
  int t = blockIdx.x * 16 + wid;
  if (tid < NE) lcnt[tid] = 0;
  __syncthreads();

  float acc[NE];
#pragma unroll
  for (int e = 0; e < NE; ++e) acc[e] = 0.f;
  const float* xr = x + (size_t)t * DM;
  unsigned int* xbr = xb + (size_t)t * (DM / 2);
#pragma unroll
  for (int j = 0; j < 4; ++j) {
    int d0 = j * 128 + lane * 2;
    float2 xv = *(const float2*)(xr + d0);
    const float* g0 = gw + d0 * NE;
#pragma unroll
    for (int e = 0; e < NE; ++e) acc[e] += xv.x * g0[e] + xv.y * g0[NE + e];
    xbr[j * 64 + lane] = f2bf1(xv.x) | (f2bf1(xv.y) << 16);
  }
#pragma unroll
  for (int off = 32; off >= 1; off >>= 1) {
#pragma unroll
    for (int e = 0; e < NE; ++e) acc[e] += __shfl_xor(acc[e], off);
  }
  if (lane == 0) {
    int e0 = 0; float l0 = acc[0];
#pragma unroll
    for (int e = 1; e < NE; ++e) if (acc[e] > l0) { l0 = acc[e]; e0 = e; }
    int e1 = (e0 == 0) ? 1 : 0; float l1 = acc[e1];
#pragma unroll
    for (int e = 0; e < NE; ++e) if (e != e0 && acc[e] > l1) { l1 = acc[e]; e1 = e; }
    float w0 = 1.f / (1.f + expf(l1 - l0));   // renormalized top-2, exact
    winfo[wid][0] = e0; winfo[wid][1] = e1;
    wval[wid][0] = w0;  wval[wid][1] = 1.f - w0;
    wslot[wid][0] = atomicAdd(&lcnt[e0], 1);
    wslot[wid][1] = atomicAdd(&lcnt[e1], 1);
  }
  __syncthreads();
  if (tid < NE) lbase[tid] = atomicAdd(&cnt[tid * 64], lcnt[tid]);
  __syncthreads();
  if (lane == 0) {
    int e0 = winfo[wid][0], e1 = winfo[wid][1];
    int p0 = lbase[e0] + wslot[wid][0];
    int p1 = lbase[e1] + wslot[wid][1];
    tok[e0 * T_TOK + p0] = t; wgt[e0 * T_TOK + p0] = wval[wid][0];
    tok[e1 * T_TOK + p1] = t; wgt[e1 * T_TOK + p1] = wval[wid][1];
  }
}

// inline per-block tile prefix (replaces plan_kernel): tb[e] = sum ceil(cnt[k]/128)
#define TILE_PREFIX(tb, cnt) \
  int tb[NE + 1]; \
  { int a_ = 0; \
    _Pragma("unroll") for (int k_ = 0; k_ < NE; ++k_) { tb[k_] = a_; a_ += (cnt[k_ * 64] + 127) >> 7; } \
    tb[NE] = a_; }

// GEMM1: H[slot][pi(f)] = gelu(gather(xb)[slot][k] @ w1t[f][k]^T + b1)
// 128x128 tile, K=512 (16 steps); 5-buffer depth-4 ring, counted vmcnt(12).
__global__ __launch_bounds__(256) void gemm1_kernel(
    const unsigned int* __restrict__ xb, const unsigned short* __restrict__ w1t,
    const float* __restrict__ b1, const int* __restrict__ cnt,
    const int* __restrict__ tok, unsigned short* __restrict__ H, int tile_lo) {
  int nwg = (int)gridDim.x;
  int bid0 = (int)blockIdx.x;
  int bid = (bid0 & 7) * (nwg >> 3) + (bid0 >> 3);   // XCD-contiguous (nwg%8==0)
  int nt = bid & 15;
  int gt = tile_lo + (bid >> 4);
  TILE_PREFIX(tb, cnt);
  if (gt >= tb[NE]) return;
  int e = 0;
#pragma unroll
  for (int k = 0; k < NE - 1; ++k) e += (gt >= tb[k + 1]) ? 1 : 0;
  int tloc = gt - tb[e];
  int ce = cnt[e * 64];
  int m0 = tloc * 128;
  int n0 = nt * 128;

  __shared__ char Lds[5 * 16384];   // 5 buffers: As 8KB + Bs 8KB each

  int tid = (int)threadIdx.x;
  int lane = tid & 63;
  int wid = tid >> 6;
  int wm = wid & 1, wn = wid >> 1;
  int fl = lane & 15, q = lane >> 4;
  int sxy = ((q ^ ((fl >> 1) & 3)) << 4);

  const int* tokg = tok + e * T_TOK;
  int r0 = tid >> 2, r1 = 64 + (tid >> 2);
  int sl = tid & 3;
  int ss0 = sl ^ ((r0 >> 1) & 3);
  int ss1 = sl ^ ((r1 >> 1) & 3);
  int t0 = tokg[min(m0 + r0, ce - 1)];
  int t1 = tokg[min(m0 + r1, ce - 1)];
  const char* asrc0 = (const char*)xb + (size_t)t0 * 1024 + ss0 * 16;
  const char* asrc1 = (const char*)xb + (size_t)t1 * 1024 + ss1 * 16;
  const char* bsrc0 = (const char*)w1t + ((size_t)e * DFF + n0 + r0) * 1024 + ss0 * 16;
  const char* bsrc1 = (const char*)w1t + ((size_t)e * DFF + n0 + r1) * 1024 + ss1 * 16;

  int aoff[4], boff[4];
#pragma unroll
  for (int i = 0; i < 4; ++i) {
    aoff[i] = (wm * 64 + i * 16 + fl) * 64 + sxy;
    boff[i] = 8192 + (wn * 64 + i * 16 + fl) * 64 + sxy;
  }

  f32x4 acc[4][4];
#pragma unroll
  for (int a = 0; a < 4; ++a)
#pragma unroll
    for (int b = 0; b < 4; ++b) acc[a][b] = (f32x4){0.f, 0.f, 0.f, 0.f};

#define STAGE1(bi, ti) do { \
    char* base_ = Lds + (bi) * 16384; size_t ko_ = (size_t)(ti) * 64; \
    GLOAD(asrc0 + ko_, base_ + tid * 16);        \
    GLOAD(asrc1 + ko_, base_ + 4096 + tid * 16); \
    GLOAD(bsrc0 + ko_, base_ + 8192 + tid * 16); \
    GLOAD(bsrc1 + ko_, base_ + 12288 + tid * 16); } while (0)

#define COMP1(bi) do { \
    const char* base_ = Lds + (bi) * 16384; \
    short8 a[4], b[4]; \
    _Pragma("unroll") for (int i = 0; i < 4; ++i) { \
      a[i] = *(const short8*)(base_ + aoff[i]); \
      b[i] = *(const short8*)(base_ + boff[i]); } \
    _Pragma("unroll") for (int mf = 0; mf < 4; ++mf) \
    _Pragma("unroll") for (int nf = 0; nf < 4; ++nf) \
      acc[mf][nf] = __builtin_amdgcn_mfma_f32_16x16x32_bf16(a[mf], b[nf], acc[mf][nf], 0, 0, 0); \
  } while (0)

#define STEP1(t, sb, cb) do { \
    WAITVM(12); BARRIER(); STAGE1(sb, (t) + 4); COMP1(cb); } while (0)

  // tiles 0..15; tile i lives in buffer i%5; depth-4 (16 loads in flight)
  STAGE1(0, 0); STAGE1(1, 1); STAGE1(2, 2); STAGE1(3, 3);
  for (int tt = 0; tt < 10; tt += 5) {        // t = 0..9, stages tiles 4..13
    STEP1(tt + 0, 4, 0);
    STEP1(tt + 1, 0, 1);
    STEP1(tt + 2, 1, 2);
    STEP1(tt + 3, 2, 3);
    STEP1(tt + 4, 3, 4);
  }
  STEP1(10, 4, 0);                                 // stages tile 14
  STEP1(11, 0, 1);                                 // stages tile 15
  WAITVM(12); BARRIER(); COMP1(2);                 // t=12
  WAITVM(8);  BARRIER(); COMP1(3);                 // t=13
  WAITVM(4);  BARRIER(); COMP1(4);                 // t=14
  WAITVM(0);  BARRIER(); COMP1(0);                 // t=15
#undef STEP1
#undef STAGE1
#undef COMP1

  // epilogue: bias + tanh-gelu; paired u32 stores at pi-permuted k positions
  size_t hrow0 = (size_t)(gt - tile_lo) * 128;
  float bv[4];
#pragma unroll
  for (int nf = 0; nf < 4; ++nf) bv[nf] = b1[e * DFF + n0 + wn * 64 + nf * 16 + fl];
#pragma unroll
  for (int mf = 0; mf < 4; ++mf)
#pragma unroll
    for (int j = 0; j < 4; ++j) {
      int row = wm * 64 + mf * 16 + q * 4 + j;
      float g[4];
#pragma unroll
      for (int nf = 0; nf < 4; ++nf) {
        float v = acc[mf][nf][j] + bv[nf];
        float u2 = v * (1.5957691216f + 0.0713548162f * v * v);
        g[nf] = v / (1.f + __expf(-u2));
      }
      unsigned int* Hp = (unsigned int*)(H + (hrow0 + row) * DFF + n0 + wn * 64);
      Hp[fl]      = f2bf1(g[0]) | (f2bf1(g[1]) << 16);
      Hp[16 + fl] = f2bf1(g[2]) | (f2bf1(g[3]) << 16);
    }
}

// GEMM2: out[tok[slot]] += wgt[slot]*(H[slot][k'] @ w2t[n][k']^T + b2[n])
// K=2048 (64 steps); 5-buffer depth-4 ring, counted vmcnt(12). (k' = pi(k), both sides.)
__global__ __launch_bounds__(256) void gemm2_kernel(
    const unsigned short* __restrict__ H, const unsigned short* __restrict__ w2t,
    const float* __restrict__ b2, const int* __restrict__ cnt,
    const int* __restrict__ tok, const float* __restrict__ wgt,
    float* __restrict__ out, int tile_lo) {
  int nwg = (int)gridDim.x;
  int bid0 = (int)blockIdx.x;
  int bid = (bid0 & 7) * (nwg >> 3) + (bid0 >> 3);   // XCD-contiguous (nwg%8==0)
  int nt = bid & 3;
  int gt = tile_lo + (bid >> 2);
  TILE_PREFIX(tb, cnt);
  if (gt >= tb[NE]) return;
  int e = 0;
#pragma unroll
  for (int k = 0; k < NE - 1; ++k) e += (gt >= tb[k + 1]) ? 1 : 0;
  int tloc = gt - tb[e];
  int ce = cnt[e * 64];
  int m0 = tloc * 128;
  int n0 = nt * 128;

  __shared__ char Lds[5 * 16384];

  int tid = (int)threadIdx.x;
  int lane = tid & 63;
  int wid = tid >> 6;
  int wm = wid & 1, wn = wid >> 1;
  int fl = lane & 15, q = lane >> 4;
  int sxy = ((q ^ ((fl >> 1) & 3)) << 4);

  int r0 = tid >> 2, r1 = 64 + (tid >> 2);
  int sl = tid & 3;
  int ss0 = sl ^ ((r0 >> 1) & 3);
  int ss1 = sl ^ ((r1 >> 1) & 3);
  size_t hrow0 = (size_t)(gt - tile_lo) * 128;
  const char* asrc0 = (const char*)H + (hrow0 + r0) * 4096 + ss0 * 16;
  const char* asrc1 = (const char*)H + (hrow0 + r1) * 4096 + ss1 * 16;
  const char* bsrc0 = (const char*)w2t + ((size_t)e * DM + n0 + r0) * 4096 + ss0 * 16;
  const char* bsrc1 = (const char*)w2t + ((size_t)e * DM + n0 + r1) * 4096 + ss1 * 16;

  int aoff[4], boff[4];
#pragma unroll
  for (int i = 0; i < 4; ++i) {
    aoff[i] = (wm * 64 + i * 16 + fl) * 64 + sxy;
    boff[i] = 8192 + (wn * 64 + i * 16 + fl) * 64 + sxy;
  }

  f32x4 acc[4][4];
#pragma unroll
  for (int a = 0; a < 4; ++a)
#pragma unroll
    for (int b = 0; b < 4; ++b) acc[a][b] = (f32x4){0.f, 0.f, 0.f, 0.f};

#define STAGE2(bi, ti) do { \
    char* base_ = Lds + (bi) * 16384; size_t ko_ = (size_t)(ti) * 64; \
    GLOAD(asrc0 + ko_, base_ + tid * 16);        \
    GLOAD(asrc1 + ko_, base_ + 4096 + tid * 16); \
    GLOAD(bsrc0 + ko_, base_ + 8192 + tid * 16); \
    GLOAD(bsrc1 + ko_, base_ + 12288 + tid * 16); } while (0)

#define COMP2(bi) do { \
    const char* base_ = Lds + (bi) * 16384; \
    short8 a[4], b[4]; \
    _Pragma("unroll") for (int i = 0; i < 4; ++i) { \
      a[i] = *(const short8*)(base_ + aoff[i]); \
      b[i] = *(const short8*)(base_ + boff[i]); } \
    _Pragma("unroll") for (int mf = 0; mf < 4; ++mf) \
    _Pragma("unroll") for (int nf = 0; nf < 4; ++nf) \
      acc[mf][nf] = __builtin_amdgcn_mfma_f32_16x16x32_bf16(a[mf], b[nf], acc[mf][nf], 0, 0, 0); \
  } while (0)

#define STEP2(t, sb, cb) do { \
    WAITVM(12); BARRIER(); STAGE2(sb, (t) + 4); COMP2(cb); } while (0)

  // tiles 0..63; tile i in buffer i%5; depth-4 (16 loads in flight)
  STAGE2(0, 0); STAGE2(1, 1); STAGE2(2, 2); STAGE2(3, 3);
  for (int tt = 0; tt < 60; tt += 5) {        // t = 0..59, stages tiles 4..63
    STEP2(tt + 0, 4, 0);
    STEP2(tt + 1, 0, 1);
    STEP2(tt + 2, 1, 2);
    STEP2(tt + 3, 2, 3);
    STEP2(tt + 4, 3, 4);
  }
  WAITVM(12); BARRIER(); COMP2(0);                 // t=60
  WAITVM(8);  BARRIER(); COMP2(1);                 // t=61
  WAITVM(4);  BARRIER(); COMP2(2);                 // t=62
  WAITVM(0);  BARRIER(); COMP2(3);                 // t=63
#undef STEP2
#undef STAGE2
#undef COMP2

  const int* tokg = tok + e * T_TOK;
  const float* wgtg = wgt + e * T_TOK;
  float bias2[4];
#pragma unroll
  for (int nf = 0; nf < 4; ++nf) bias2[nf] = b2[e * DM + n0 + wn * 64 + nf * 16 + fl];
#pragma unroll
  for (int mf = 0; mf < 4; ++mf)
#pragma unroll
    for (int j = 0; j < 4; ++j) {
      int row = wm * 64 + mf * 16 + q * 4 + j;
      int slot = m0 + row;
      if (slot < ce) {
        int tk = tokg[slot];
        float w = wgtg[slot];
        float* orow = out + (size_t)tk * DM + n0 + wn * 64;
#pragma unroll
        for (int nf = 0; nf < 4; ++nf)
          atomicAdd(orow + nf * 16 + fl, w * (acc[mf][nf][j] + bias2[nf]));
      }
    }
}

extern "C" void kernel_launch(void* const* d_in, const int* in_sizes, int n_in,
                              void* d_out, int out_size, void* d_ws, size_t ws_size,
                              hipStream_t stream) {
  (void)in_sizes; (void)n_in; (void)out_size;
  const float* x  = (const float*)d_in[0];
  const float* gw = (const float*)d_in[1];
  const float* w1 = (const float*)d_in[2];
  const float* b1 = (const float*)d_in[3];
  const float* w2 = (const float*)d_in[4];
  const float* b2 = (const float*)d_in[5];
  float* out = (float*)d_out;

  char* ws = (char*)d_ws;
  size_t off = 0;
  auto alloc = [&](size_t sz) { char* p = ws + off; off += (sz + 255) & ~(size_t)255; return p; };
  int*   cnt = (int*)alloc(NE * 64 * 4);
  int*   tok = (int*)alloc((size_t)NE * T_TOK * 4);
  float* wgt = (float*)alloc((size_t)NE * T_TOK * 4);
  unsigned int* xb = (unsigned int*)alloc((size_t)T_TOK * (DM / 2) * 4);
  unsigned short* w1t = (unsigned short*)alloc((size_t)NE * DFF * DM * 2);
  unsigned short* w2t = (unsigned short*)alloc((size_t)NE * DM * DFF * 2);

  // Chunking: TPC=256 -> gemm2 grid 1024 = exactly 2.0 rounds at 2 blk/CU;
  // gemm1 grid 4096 = exactly 8.0 rounds. Chunks: 256/256/16.
  size_t avail = (ws_size > off) ? (ws_size - off) : 0;
  int TPC = 256;
  while (TPC > 4 && (size_t)TPC * 128 * DFF * 2 > avail) TPC >>= 1;
  unsigned short* H = (unsigned short*)alloc((size_t)TPC * 128 * DFF * 2);

  hipMemsetAsync(cnt, 0, NE * 64 * 4, stream);
  hipMemsetAsync(out, 0, (size_t)T_TOK * DM * 4, stream);

  tcvt_all_kernel<<<16384, dim3(32, 8), 0, stream>>>(w1, w2, w1t, w2t);
  gate_kernel<<<T_TOK / 16, 1024, 0, stream>>>(x, gw, cnt, tok, wgt, xb);

  for (int lo = 0; lo < MAXTILES; lo += TPC) {
    gemm1_kernel<<<TPC * 16, 256, 0, stream>>>(xb, w1t, b1, cnt, tok, H, lo);
    gemm2_kernel<<<TPC * 4, 256, 0, stream>>>(H, w2t, b2, cnt, tok, wgt, out, lo);
  }
}